// Round 12
// baseline (206.393 us; speedup 1.0000x reference)
//
#include <hip/hip_runtime.h>
#include <hip/hip_bf16.h>
#include <math.h>

#define B_ 2
#define T_ 2048
#define C_ 1024
#define H_ 16
#define D_ 64

typedef __attribute__((ext_vector_type(8))) short short8;
typedef __attribute__((ext_vector_type(4))) short short4v;
typedef __attribute__((ext_vector_type(4))) float f32x4;

static __device__ __forceinline__ short f2bf(float f) {
    return (short)__builtin_bit_cast(unsigned short, __float2bfloat16(f));
}

// v_mfma_f32_16x16x32_bf16 (A,B: bf16x8 in 4 VGPRs; C/D: f32x4).
// s_nop 1 guards VALU-write -> MFMA-read operand hazard.
static __device__ __forceinline__ f32x4 mfma16(short8 a, short8 b, f32x4 c) {
    asm volatile("s_nop 1\n\tv_mfma_f32_16x16x32_bf16 %0, %1, %2, %0"
                 : "+v"(c) : "v"(a), "v"(b));
    return c;
}

// MFMA-cluster -> VALU-read-of-acc hazard guard (rule #18 fencing).
static __device__ __forceinline__ void mfma_drain() {
    __builtin_amdgcn_sched_barrier(0);
    asm volatile("s_nop 7\n\ts_nop 7");
    __builtin_amdgcn_sched_barrier(0);
}

// async global->LDS, 16B/lane; LDS dest is wave-uniform base (+lane*16 implicit)
static __device__ __forceinline__ void gload16(const void* g, void* l) {
    __builtin_amdgcn_global_load_lds((const __attribute__((address_space(1))) void*)g,
                                     (__attribute__((address_space(3))) void*)l, 16, 0, 0);
}

// ---------------------------------------------------------------------------
// fp32 -> bf16 pre-convert: x (4M els) + Wq/Wk/Wv/Wo (1M each), vec8 grid-stride
// ---------------------------------------------------------------------------
__global__ __launch_bounds__(256)
void cvt_all(const float* __restrict__ x,  const float* __restrict__ wq,
             const float* __restrict__ wk, const float* __restrict__ wv,
             const float* __restrict__ wo,
             short* __restrict__ xb,  short* __restrict__ wqb,
             short* __restrict__ wkb, short* __restrict__ wvb,
             short* __restrict__ wob)
{
    const int XV = 524288, WV = 131072, TOT = 1048576;   // vec8 counts
    for (int i = blockIdx.x * blockDim.x + threadIdx.x; i < TOT;
         i += gridDim.x * blockDim.x) {
        const float* s; short* d; int off;
        if (i < XV) { s = x; d = xb; off = i; }
        else {
            const int j = i - XV, r = j >> 17;
            off = j & (WV - 1);
            s = (r == 0) ? wq  : (r == 1) ? wk  : (r == 2) ? wv  : wo;
            d = (r == 0) ? wqb : (r == 1) ? wkb : (r == 2) ? wvb : wob;
        }
        const float4 f0 = *(const float4*)(s + (size_t)off * 8);
        const float4 f1 = *(const float4*)(s + (size_t)off * 8 + 4);
        short8 o;
        o[0]=f2bf(f0.x); o[1]=f2bf(f0.y); o[2]=f2bf(f0.z); o[3]=f2bf(f0.w);
        o[4]=f2bf(f1.x); o[5]=f2bf(f1.y); o[6]=f2bf(f1.z); o[7]=f2bf(f1.w);
        *(short8*)(d + (size_t)off * 8) = o;
    }
}

// ---------------------------------------------------------------------------
// bf16 NT GEMM core (m97 structure): MT*16-row x 128-col tile, BK=32,
// 4 waves (2x2 quadrants), global_load_lds(16B) linear-LDS staging,
// 2 barriers per K-step, MT*4 MFMA per wave per K-step. K fixed = 1024.
// ---------------------------------------------------------------------------
template<int MT>
static __device__ __forceinline__ void gemm_core_bf16(
    const short* __restrict__ A, const short* __restrict__ W,
    short* Asl, short* Bsl, int m0, int n0, f32x4 (&acc)[MT][4])
{
    const int tid = threadIdx.x;
    const int wid = tid >> 6, l = tid & 63;
    const int lr  = l & 15,  lg = l >> 4;
    const int wr  = wid >> 1, wc = wid & 1;
    const int srA = MT*8*wid + (l >> 2);   // A stage row (+16*i)
    const int srB = 32*wid  + (l >> 2);    // B stage row (+16*i)
    const int ske = (l & 3) * 8;           // k-el offset within 32
    short* lA = Asl + MT*256*wid;          // wave-uniform LDS bases
    short* lB = Bsl + 1024*wid;
    for (int kc = 0; kc < 1024; kc += 32) {
        #pragma unroll
        for (int i = 0; i < MT/2; ++i)
            gload16(&A[(size_t)(m0 + srA + 16*i) * 1024 + kc + ske], lA + 512*i);
        #pragma unroll
        for (int i = 0; i < 2; ++i)
            gload16(&W[(size_t)(n0 + srB + 16*i) * 1024 + kc + ske], lB + 512*i);
        __syncthreads();                    // drains vmcnt -> staged data visible
        short8 af[MT], bfr[4];
        #pragma unroll
        for (int mi = 0; mi < MT; ++mi)
            af[mi] = *(const short8*)&Asl[(MT*16*wr + 16*mi + lr) * 32 + lg*8];
        #pragma unroll
        for (int ni = 0; ni < 4; ++ni)
            bfr[ni] = *(const short8*)&Bsl[(64*wc + 16*ni + lr) * 32 + lg*8];
        #pragma unroll
        for (int mi = 0; mi < MT; ++mi)
            #pragma unroll
            for (int ni = 0; ni < 4; ++ni)
                acc[mi][ni] = mfma16(af[mi], bfr[ni], acc[mi][ni]);
        __syncthreads();                    // protect LDS before next stage
    }
}

// Fused QKV projection: grid (32, 24); y-block 0..7 -> Q, 8..15 -> K, 16..23 -> V.
// Q,K -> bf16 [B,H,T,D]; V -> bf16 [B,H,D,T]. Q is PRE-SCALED by 1/sqrt(D)*log2e
// so attention's S comes out of MFMA already in exp2 units.
__global__ __launch_bounds__(256)
void qkv_gemm(const short* __restrict__ xb,  const short* __restrict__ wqb,
              const short* __restrict__ wkb, const short* __restrict__ wvb,
              const float* __restrict__ bq,  const float* __restrict__ bk,
              const float* __restrict__ bv,
              short* __restrict__ q, short* __restrict__ k, short* __restrict__ v)
{
    __shared__ __attribute__((aligned(16))) short Asl[128*32];
    __shared__ __attribute__((aligned(16))) short Bsl[128*32];
    const int m0 = blockIdx.x * 128;
    const int nyg = blockIdx.y;
    const int region = nyg >> 3;           // 0:Q 1:K 2:V
    const int n0 = (nyg & 7) * 128;
    const short* W    = (region == 0) ? wqb : (region == 1) ? wkb : wvb;
    const float* bias = (region == 0) ? bq  : (region == 1) ? bk  : bv;
    f32x4 acc[4][4] = {};
    gemm_core_bf16<4>(xb, W, Asl, Bsl, m0, n0, acc);
    mfma_drain();                          // MFMA -> VALU read hazard
    const int tid = threadIdx.x;
    const int wid = tid >> 6, l = tid & 63;
    const int lr = l & 15, lg = l >> 4;
    const int wr = wid >> 1, wc = wid & 1;
    const float qscl = 0.125f * 1.44269504f;
    if (region < 2) {
        short* outp = (region == 0) ? q : k;
        const float scl = (region == 0) ? qscl : 1.0f;
        #pragma unroll
        for (int mi = 0; mi < 4; ++mi) {
            #pragma unroll
            for (int ni = 0; ni < 4; ++ni) {
                const int n = n0 + 64*wc + 16*ni + lr;
                const float bn = bias[n];
                const int h = n >> 6, d = n & 63;
                #pragma unroll
                for (int r = 0; r < 4; ++r) {
                    const int m = m0 + 64*wr + 16*mi + 4*lg + r;
                    const int bb = m >> 11, tt = m & 2047;
                    outp[((((size_t)bb*H_ + h)*T_ + tt) << 6) + d] =
                        f2bf((acc[mi][ni][r] + bn) * scl);
                }
            }
        }
    } else {
        #pragma unroll
        for (int mi = 0; mi < 4; ++mi) {
            const int m = m0 + 64*wr + 16*mi + 4*lg;   // 4 consecutive tt
            const int bb = m >> 11, tt = m & 2047;
            #pragma unroll
            for (int ni = 0; ni < 4; ++ni) {
                const int n = n0 + 64*wc + 16*ni + lr;
                const float bn = bias[n];
                const int h = n >> 6, d = n & 63;
                short4v ov;
                #pragma unroll
                for (int r = 0; r < 4; ++r) ov[r] = f2bf(acc[mi][ni][r] + bn);
                *(short4v*)&v[((((size_t)bb*H_ + h)*D_ + d) << 11) + tt] = ov;
            }
        }
    }
}

// Output projection: ya[4096][1024] bf16 x Wo[1024][1024] bf16 -> fp32 out.
__global__ __launch_bounds__(256)
void out_gemm(const short* __restrict__ ya, const short* __restrict__ wo,
              const float* __restrict__ bo, float* __restrict__ out)
{
    __shared__ __attribute__((aligned(16))) short Asl[64*32];
    __shared__ __attribute__((aligned(16))) short Bsl[128*32];
    const int m0 = blockIdx.x * 64;
    const int n0 = blockIdx.y * 128;
    f32x4 acc[2][4] = {};
    gemm_core_bf16<2>(ya, wo, Asl, Bsl, m0, n0, acc);
    mfma_drain();
    const int tid = threadIdx.x;
    const int wid = tid >> 6, l = tid & 63;
    const int lr = l & 15, lg = l >> 4;
    const int wr = wid >> 1, wc = wid & 1;
    #pragma unroll
    for (int mi = 0; mi < 2; ++mi) {
        #pragma unroll
        for (int ni = 0; ni < 4; ++ni) {
            const int n = n0 + 64*wc + 16*ni + lr;
            const float bn = bo[n];
            #pragma unroll
            for (int r = 0; r < 4; ++r) {
                const int m = m0 + 32*wr + 16*mi + 4*lg + r;
                out[(size_t)m * C_ + n] = acc[mi][ni][r] + bn;
            }
        }
    }
}

// ---------------------------------------------------------------------------
// Causal flash attention v3: PAIRED q-tiles for perfect causal load balance.
// Block = 4 waves, owns q-tiles (pr, 31-pr) of one head -> exactly 33
// tile-computes per block; each staged K/V tile feeds up to TWO q-tiles
// (32 MFMA per barrier pair). Grid = 32 heads x 16 pairs = 512 equal blocks.
// Swapped operands: S^T = mfma(K,Q), O^T = mfma(V^T,P); softmax lane-local.
// Q arrives pre-scaled (exp2 units). LDS stride 88 shorts (b128-aligned).
// ---------------------------------------------------------------------------
#define PAD 88

// one q-tile's online-softmax step for one staged K/V tile
template<bool DIAG>
static __device__ __forceinline__ void attn_step(
    const short (*Ks)[PAD], const short (*Vs)[PAD], short (*Psw)[PAD],
    const short8 (&qfrag)[2], int k0, int qrow, int lr, int lg,
    float& m_i, float& l_i, f32x4 (&oacc)[4])
{
    f32x4 sacc[4] = {};
    #pragma unroll
    for (int mt = 0; mt < 4; ++mt) {
        #pragma unroll
        for (int kc = 0; kc < 2; ++kc) {
            const short8 kf = *(const short8*)&Ks[16*mt + lr][32*kc + 8*lg];
            sacc[mt] = mfma16(kf, qfrag[kc], sacc[mt]);
        }
    }
    mfma_drain();                          // MFMA -> VALU read hazard

    float mloc = m_i;
    float sv[16];
    #pragma unroll
    for (int mt = 0; mt < 4; ++mt)
        #pragma unroll
        for (int r = 0; r < 4; ++r) {
            float s = sacc[mt][r];         // already in exp2 units
            if (DIAG && (k0 + 16*mt + 4*lg + r) > qrow) s = -INFINITY;
            sv[mt*4+r] = s;
            mloc = fmaxf(mloc, s);
        }
    mloc = fmaxf(mloc, __shfl_xor(mloc, 16));
    mloc = fmaxf(mloc, __shfl_xor(mloc, 32));
    const float alpha = exp2f(m_i - mloc);
    float lsum = 0.f;
    #pragma unroll
    for (int mt = 0; mt < 4; ++mt) {
        short4v pk;
        #pragma unroll
        for (int r = 0; r < 4; ++r) {
            const float p = exp2f(sv[mt*4+r] - mloc);
            lsum += p;
            pk[r] = f2bf(p);
        }
        *(short4v*)&Psw[lr][16*mt + 4*lg] = pk;   // P[q=lr][k]
    }
    lsum += __shfl_xor(lsum, 16);
    lsum += __shfl_xor(lsum, 32);
    l_i = l_i * alpha + lsum;
    m_i = mloc;
    #pragma unroll
    for (int mt = 0; mt < 4; ++mt) {
        oacc[mt][0] *= alpha; oacc[mt][1] *= alpha;
        oacc[mt][2] *= alpha; oacc[mt][3] *= alpha;
    }
    // PV: oacc[mt] += mfma(V^T strip, P). Per-wave DS ordering guarantees the
    // ds_reads of Psw here complete before the next attn_step's overwrites.
    #pragma unroll
    for (int kc = 0; kc < 2; ++kc) {
        const short8 pf = *(const short8*)&Psw[lr][32*kc + 8*lg];
        #pragma unroll
        for (int mt = 0; mt < 4; ++mt) {
            const short8 vf = *(const short8*)&Vs[16*mt + lr][32*kc + 8*lg];
            oacc[mt] = mfma16(vf, pf, oacc[mt]);
        }
    }
}

__global__ __launch_bounds__(256)
void attn_mfma(const short* __restrict__ Q, const short* __restrict__ K,
               const short* __restrict__ Vt, short* __restrict__ out)
{
    __shared__ __attribute__((aligned(16))) short Ks[64][PAD];    // [k][d]
    __shared__ __attribute__((aligned(16))) short Vs[64][PAD];    // [d][k]
    __shared__ __attribute__((aligned(16))) short Ps[4][16][PAD]; // per-wave [q][k]

    const int id = blockIdx.x;
    const int bh = id >> 4;            // head index (32)
    const int pr = id & 15;            // pair index
    const int qtA = pr, qtB = 31 - pr; // qtA in [0,15], qtB in [16,31]
    const int b = bh >> 4, h = bh & 15;
    const int tid = threadIdx.x;
    const int w = tid >> 6, l = tid & 63;
    const int lr = l & 15, lg = l >> 4;

    const short* Qp = Q  + (size_t)bh * T_ * D_;
    const short* Kp = K  + (size_t)bh * T_ * D_;
    const short* Vp = Vt + (size_t)bh * D_ * T_;

    // staging coords: thread owns rows {sr0, sr0+32}, 8-col chunk sc
    const int sr0 = tid >> 3;          // 0..31
    const int sc  = (tid & 7) * 8;     // 0..56

    // prologue: prefetch tile 0 into regs
    short8 kreg[2], vreg[2];
    kreg[0] = *(const short8*)(Kp + (size_t)sr0 * D_ + sc);
    kreg[1] = *(const short8*)(Kp + (size_t)(sr0 + 32) * D_ + sc);
    vreg[0] = *(const short8*)(Vp + (size_t)sr0 * T_ + sc);
    vreg[1] = *(const short8*)(Vp + (size_t)(sr0 + 32) * T_ + sc);

    const int qrowA = qtA * 64 + 16*w + lr;
    const int qrowB = qtB * 64 + 16*w + lr;
    short8 qfragA[2], qfragB[2];
    {
        const short* qa = Qp + (size_t)qrowA * D_ + lg * 8;
        const short* qb = Qp + (size_t)qrowB * D_ + lg * 8;
        qfragA[0] = *(const short8*)(qa); qfragA[1] = *(const short8*)(qa + 32);
        qfragB[0] = *(const short8*)(qb); qfragB[1] = *(const short8*)(qb + 32);
    }

    float mA = -INFINITY, lA = 0.f, mB = -INFINITY, lB = 0.f;
    f32x4 oaccA[4] = {}, oaccB[4] = {};

    for (int kt = 0; kt <= qtB; ++kt) {
        const int k0 = kt * 64;
        __syncthreads();                       // prev compute done reading LDS
        *(short8*)&Ks[sr0][sc]      = kreg[0];
        *(short8*)&Ks[sr0 + 32][sc] = kreg[1];
        *(short8*)&Vs[sr0][sc]      = vreg[0];
        *(short8*)&Vs[sr0 + 32][sc] = vreg[1];
        __syncthreads();                       // LDS ready

        if (kt < qtB) {                        // issue prefetch for tile kt+1
            const int k1 = k0 + 64;
            kreg[0] = *(const short8*)(Kp + (size_t)(k1 + sr0) * D_ + sc);
            kreg[1] = *(const short8*)(Kp + (size_t)(k1 + sr0 + 32) * D_ + sc);
            vreg[0] = *(const short8*)(Vp + (size_t)sr0 * T_ + k1 + sc);
            vreg[1] = *(const short8*)(Vp + (size_t)(sr0 + 32) * T_ + k1 + sc);
        }

        // tile B (always active; diag only on last iteration)
        if (kt == qtB)
            attn_step<true >(Ks, Vs, Ps[w], qfragB, k0, qrowB, lr, lg, mB, lB, oaccB);
        else
            attn_step<false>(Ks, Vs, Ps[w], qfragB, k0, qrowB, lr, lg, mB, lB, oaccB);

        // tile A (active while kt <= qtA)
        if (kt < qtA)
            attn_step<false>(Ks, Vs, Ps[w], qfragA, k0, qrowA, lr, lg, mA, lA, oaccA);
        else if (kt == qtA)
            attn_step<true >(Ks, Vs, Ps[w], qfragA, k0, qrowA, lr, lg, mA, lA, oaccA);
    }
    mfma_drain();

    const float invA = 1.f / lA;
    const float invB = 1.f / lB;
    short* opA = out + ((size_t)(b * T_ + qrowA)) * C_ + h * D_;
    short* opB = out + ((size_t)(b * T_ + qrowB)) * C_ + h * D_;
    #pragma unroll
    for (int mt = 0; mt < 4; ++mt) {
        short4v oa, ob;
        oa[0] = f2bf(oaccA[mt][0] * invA); oa[1] = f2bf(oaccA[mt][1] * invA);
        oa[2] = f2bf(oaccA[mt][2] * invA); oa[3] = f2bf(oaccA[mt][3] * invA);
        ob[0] = f2bf(oaccB[mt][0] * invB); ob[1] = f2bf(oaccB[mt][1] * invB);
        ob[2] = f2bf(oaccB[mt][2] * invB); ob[3] = f2bf(oaccB[mt][3] * invB);
        *(short4v*)&opA[16*mt + 4*lg] = oa;
        *(short4v*)&opB[16*mt + 4*lg] = ob;
    }
}

// ---------------------------------------------------------------------------
extern "C" void kernel_launch(void* const* d_in, const int* in_sizes, int n_in,
                              void* d_out, int out_size, void* d_ws, size_t ws_size,
                              hipStream_t stream) {
    const float* x  = (const float*)d_in[0];
    const float* Wq = (const float*)d_in[1];
    const float* bq = (const float*)d_in[2];
    const float* Wk = (const float*)d_in[3];
    const float* bk = (const float*)d_in[4];
    const float* Wv = (const float*)d_in[5];
    const float* bv = (const float*)d_in[6];
    const float* Wo = (const float*)d_in[7];
    const float* bo = (const float*)d_in[8];
    float* out = (float*)d_out;

    // bf16 workspace (els): x 4M | Wq..Wo 1M each | Q,K,V^T 4M each | ya 4M = 48MB
    short* xb  = (short*)d_ws;
    short* wqb = xb  + 4194304;
    short* wkb = wqb + 1048576;
    short* wvb = wkb + 1048576;
    short* wob = wvb + 1048576;
    short* qb  = wob + 1048576;
    short* kb  = qb  + 4194304;
    short* vb  = kb  + 4194304;   // V^T [B,H,D,T]
    short* yab = vb  + 4194304;   // [B,T,C]

    cvt_all<<<1024, 256, 0, stream>>>(x, Wq, Wk, Wv, Wo, xb, wqb, wkb, wvb, wob);
    qkv_gemm<<<dim3(32, 24), 256, 0, stream>>>(xb, wqb, wkb, wvb, bq, bk, bv,
                                               qb, kb, vb);
    attn_mfma<<<dim3(512), 256, 0, stream>>>(qb, kb, vb, yab);
    out_gemm<<<dim3(64, 8), 256, 0, stream>>>(yab, wob, bo, out);
}

// Round 13
// 205.043 us; speedup vs baseline: 1.0066x; 1.0066x over previous
//
#include <hip/hip_runtime.h>
#include <hip/hip_bf16.h>
#include <math.h>

#define B_ 2
#define T_ 2048
#define C_ 1024
#define H_ 16
#define D_ 64

typedef __attribute__((ext_vector_type(8))) short short8;
typedef __attribute__((ext_vector_type(4))) short short4v;
typedef __attribute__((ext_vector_type(4))) float f32x4;

static __device__ __forceinline__ short f2bf(float f) {
    return (short)__builtin_bit_cast(unsigned short, __float2bfloat16(f));
}

// v_mfma_f32_16x16x32_bf16 (A,B: bf16x8 in 4 VGPRs; C/D: f32x4).
// s_nop 1 guards VALU-write -> MFMA-read operand hazard.
static __device__ __forceinline__ f32x4 mfma16(short8 a, short8 b, f32x4 c) {
    asm volatile("s_nop 1\n\tv_mfma_f32_16x16x32_bf16 %0, %1, %2, %0"
                 : "+v"(c) : "v"(a), "v"(b));
    return c;
}

// MFMA-cluster -> VALU-read-of-acc hazard guard (rule #18 fencing).
static __device__ __forceinline__ void mfma_drain() {
    __builtin_amdgcn_sched_barrier(0);
    asm volatile("s_nop 7\n\ts_nop 7");
    __builtin_amdgcn_sched_barrier(0);
}

// async global->LDS, 16B/lane; LDS dest is wave-uniform base (+lane*16 implicit)
static __device__ __forceinline__ void gload16(const void* g, void* l) {
    __builtin_amdgcn_global_load_lds((const __attribute__((address_space(1))) void*)g,
                                     (__attribute__((address_space(3))) void*)l, 16, 0, 0);
}

// ---------------------------------------------------------------------------
// fp32 -> bf16 pre-convert: x (4M els) + Wq/Wk/Wv/Wo (1M each), vec8 grid-stride
// ---------------------------------------------------------------------------
__global__ __launch_bounds__(256)
void cvt_all(const float* __restrict__ x,  const float* __restrict__ wq,
             const float* __restrict__ wk, const float* __restrict__ wv,
             const float* __restrict__ wo,
             short* __restrict__ xb,  short* __restrict__ wqb,
             short* __restrict__ wkb, short* __restrict__ wvb,
             short* __restrict__ wob)
{
    const int XV = 524288, WV = 131072, TOT = 1048576;   // vec8 counts
    for (int i = blockIdx.x * blockDim.x + threadIdx.x; i < TOT;
         i += gridDim.x * blockDim.x) {
        const float* s; short* d; int off;
        if (i < XV) { s = x; d = xb; off = i; }
        else {
            const int j = i - XV, r = j >> 17;
            off = j & (WV - 1);
            s = (r == 0) ? wq  : (r == 1) ? wk  : (r == 2) ? wv  : wo;
            d = (r == 0) ? wqb : (r == 1) ? wkb : (r == 2) ? wvb : wob;
        }
        const float4 f0 = *(const float4*)(s + (size_t)off * 8);
        const float4 f1 = *(const float4*)(s + (size_t)off * 8 + 4);
        short8 o;
        o[0]=f2bf(f0.x); o[1]=f2bf(f0.y); o[2]=f2bf(f0.z); o[3]=f2bf(f0.w);
        o[4]=f2bf(f1.x); o[5]=f2bf(f1.y); o[6]=f2bf(f1.z); o[7]=f2bf(f1.w);
        *(short8*)(d + (size_t)off * 8) = o;
    }
}

// ---------------------------------------------------------------------------
// bf16 NT GEMM core (m97 structure): MT*16-row x 128-col tile, BK=32,
// 4 waves (2x2 quadrants), global_load_lds(16B) linear-LDS staging,
// 2 barriers per K-step, MT*4 MFMA per wave per K-step. K fixed = 1024.
// ---------------------------------------------------------------------------
template<int MT>
static __device__ __forceinline__ void gemm_core_bf16(
    const short* __restrict__ A, const short* __restrict__ W,
    short* Asl, short* Bsl, int m0, int n0, f32x4 (&acc)[MT][4])
{
    const int tid = threadIdx.x;
    const int wid = tid >> 6, l = tid & 63;
    const int lr  = l & 15,  lg = l >> 4;
    const int wr  = wid >> 1, wc = wid & 1;
    const int srA = MT*8*wid + (l >> 2);   // A stage row (+16*i)
    const int srB = 32*wid  + (l >> 2);    // B stage row (+16*i)
    const int ske = (l & 3) * 8;           // k-el offset within 32
    short* lA = Asl + MT*256*wid;          // wave-uniform LDS bases
    short* lB = Bsl + 1024*wid;
    for (int kc = 0; kc < 1024; kc += 32) {
        #pragma unroll
        for (int i = 0; i < MT/2; ++i)
            gload16(&A[(size_t)(m0 + srA + 16*i) * 1024 + kc + ske], lA + 512*i);
        #pragma unroll
        for (int i = 0; i < 2; ++i)
            gload16(&W[(size_t)(n0 + srB + 16*i) * 1024 + kc + ske], lB + 512*i);
        __syncthreads();                    // drains vmcnt -> staged data visible
        short8 af[MT], bfr[4];
        #pragma unroll
        for (int mi = 0; mi < MT; ++mi)
            af[mi] = *(const short8*)&Asl[(MT*16*wr + 16*mi + lr) * 32 + lg*8];
        #pragma unroll
        for (int ni = 0; ni < 4; ++ni)
            bfr[ni] = *(const short8*)&Bsl[(64*wc + 16*ni + lr) * 32 + lg*8];
        #pragma unroll
        for (int mi = 0; mi < MT; ++mi)
            #pragma unroll
            for (int ni = 0; ni < 4; ++ni)
                acc[mi][ni] = mfma16(af[mi], bfr[ni], acc[mi][ni]);
        __syncthreads();                    // protect LDS before next stage
    }
}

// Fused QKV projection: grid (32, 24); y-block 0..7 -> Q, 8..15 -> K, 16..23 -> V.
// Q,K -> bf16 [B,H,T,D]; V -> bf16 [B,H,D,T]. Q is PRE-SCALED by 1/sqrt(D)*log2e
// so attention's S comes out of MFMA already in exp2 units.
__global__ __launch_bounds__(256)
void qkv_gemm(const short* __restrict__ xb,  const short* __restrict__ wqb,
              const short* __restrict__ wkb, const short* __restrict__ wvb,
              const float* __restrict__ bq,  const float* __restrict__ bk,
              const float* __restrict__ bv,
              short* __restrict__ q, short* __restrict__ k, short* __restrict__ v)
{
    __shared__ __attribute__((aligned(16))) short Asl[128*32];
    __shared__ __attribute__((aligned(16))) short Bsl[128*32];
    const int m0 = blockIdx.x * 128;
    const int nyg = blockIdx.y;
    const int region = nyg >> 3;           // 0:Q 1:K 2:V
    const int n0 = (nyg & 7) * 128;
    const short* W    = (region == 0) ? wqb : (region == 1) ? wkb : wvb;
    const float* bias = (region == 0) ? bq  : (region == 1) ? bk  : bv;
    f32x4 acc[4][4] = {};
    gemm_core_bf16<4>(xb, W, Asl, Bsl, m0, n0, acc);
    mfma_drain();                          // MFMA -> VALU read hazard
    const int tid = threadIdx.x;
    const int wid = tid >> 6, l = tid & 63;
    const int lr = l & 15, lg = l >> 4;
    const int wr = wid >> 1, wc = wid & 1;
    const float qscl = 0.125f * 1.44269504f;
    if (region < 2) {
        short* outp = (region == 0) ? q : k;
        const float scl = (region == 0) ? qscl : 1.0f;
        #pragma unroll
        for (int mi = 0; mi < 4; ++mi) {
            #pragma unroll
            for (int ni = 0; ni < 4; ++ni) {
                const int n = n0 + 64*wc + 16*ni + lr;
                const float bn = bias[n];
                const int h = n >> 6, d = n & 63;
                #pragma unroll
                for (int r = 0; r < 4; ++r) {
                    const int m = m0 + 64*wr + 16*mi + 4*lg + r;
                    const int bb = m >> 11, tt = m & 2047;
                    outp[((((size_t)bb*H_ + h)*T_ + tt) << 6) + d] =
                        f2bf((acc[mi][ni][r] + bn) * scl);
                }
            }
        }
    } else {
        #pragma unroll
        for (int mi = 0; mi < 4; ++mi) {
            const int m = m0 + 64*wr + 16*mi + 4*lg;   // 4 consecutive tt
            const int bb = m >> 11, tt = m & 2047;
            #pragma unroll
            for (int ni = 0; ni < 4; ++ni) {
                const int n = n0 + 64*wc + 16*ni + lr;
                const float bn = bias[n];
                const int h = n >> 6, d = n & 63;
                short4v ov;
                #pragma unroll
                for (int r = 0; r < 4; ++r) ov[r] = f2bf(acc[mi][ni][r] + bn);
                *(short4v*)&v[((((size_t)bb*H_ + h)*D_ + d) << 11) + tt] = ov;
            }
        }
    }
}

// Output projection: ya[4096][1024] bf16 x Wo[1024][1024] bf16 -> fp32 out.
__global__ __launch_bounds__(256)
void out_gemm(const short* __restrict__ ya, const short* __restrict__ wo,
              const float* __restrict__ bo, float* __restrict__ out)
{
    __shared__ __attribute__((aligned(16))) short Asl[64*32];
    __shared__ __attribute__((aligned(16))) short Bsl[128*32];
    const int m0 = blockIdx.x * 64;
    const int n0 = blockIdx.y * 128;
    f32x4 acc[2][4] = {};
    gemm_core_bf16<2>(ya, wo, Asl, Bsl, m0, n0, acc);
    mfma_drain();
    const int tid = threadIdx.x;
    const int wid = tid >> 6, l = tid & 63;
    const int lr = l & 15, lg = l >> 4;
    const int wr = wid >> 1, wc = wid & 1;
    #pragma unroll
    for (int mi = 0; mi < 2; ++mi) {
        #pragma unroll
        for (int ni = 0; ni < 4; ++ni) {
            const int n = n0 + 64*wc + 16*ni + lr;
            const float bn = bo[n];
            #pragma unroll
            for (int r = 0; r < 4; ++r) {
                const int m = m0 + 32*wr + 16*mi + 4*lg + r;
                out[(size_t)m * C_ + n] = acc[mi][ni][r] + bn;
            }
        }
    }
}

// ---------------------------------------------------------------------------
// Causal flash attention v4: paired q-tiles (pr, 31-pr) + double-buffered K/V
// (ONE barrier per staged tile) + fence-free dual phases (QK^T A,B -> one
// drain -> softmax+PV A,B in one scheduling region so the compiler
// interleaves the two independent softmax chains).
// Swapped operands: S^T = mfma(K,Q), O^T = mfma(V^T,P); softmax lane-local.
// Q arrives pre-scaled (exp2 units). LDS stride 88 shorts (b128-aligned).
// LDS: K dbuf 22.5K + V dbuf 22.5K + Ps 11.3K = 55K -> 2 blocks/CU (= grid cap).
// ---------------------------------------------------------------------------
#define PAD 88

static __device__ __forceinline__ void qk_phase(
    const short (*Ksb)[PAD], const short8 (&qf)[2], int lr, int lg,
    f32x4 (&sacc)[4])
{
    #pragma unroll
    for (int mt = 0; mt < 4; ++mt) {
        #pragma unroll
        for (int kc = 0; kc < 2; ++kc) {
            const short8 kf = *(const short8*)&Ksb[16*mt + lr][32*kc + 8*lg];
            sacc[mt] = mfma16(kf, qf[kc], sacc[mt]);
        }
    }
}

template<bool DIAG>
static __device__ __forceinline__ void sm_pv_phase(
    f32x4 (&sacc)[4], const short (*Vsb)[PAD], short (*Psw)[PAD],
    int k0, int qrow, int lr, int lg,
    float& m_i, float& l_i, f32x4 (&oacc)[4])
{
    float mloc = m_i;
    #pragma unroll
    for (int mt = 0; mt < 4; ++mt)
        #pragma unroll
        for (int r = 0; r < 4; ++r) {
            float s = sacc[mt][r];         // already in exp2 units
            if (DIAG && (k0 + 16*mt + 4*lg + r) > qrow) s = -INFINITY;
            sacc[mt][r] = s;
            mloc = fmaxf(mloc, s);
        }
    mloc = fmaxf(mloc, __shfl_xor(mloc, 16));
    mloc = fmaxf(mloc, __shfl_xor(mloc, 32));
    const float alpha = exp2f(m_i - mloc);
    float lsum = 0.f;
    #pragma unroll
    for (int mt = 0; mt < 4; ++mt) {
        short4v pk;
        #pragma unroll
        for (int r = 0; r < 4; ++r) {
            const float p = exp2f(sacc[mt][r] - mloc);
            lsum += p;
            pk[r] = f2bf(p);
        }
        *(short4v*)&Psw[lr][16*mt + 4*lg] = pk;   // P[q=lr][k]
    }
    lsum += __shfl_xor(lsum, 16);
    lsum += __shfl_xor(lsum, 32);
    l_i = l_i * alpha + lsum;
    m_i = mloc;
    #pragma unroll
    for (int mt = 0; mt < 4; ++mt) {
        oacc[mt][0] *= alpha; oacc[mt][1] *= alpha;
        oacc[mt][2] *= alpha; oacc[mt][3] *= alpha;
    }
    // PV: per-wave in-order DS guarantees these reads finish before any later
    // reuse-writes of Psw by this wave.
    #pragma unroll
    for (int kc = 0; kc < 2; ++kc) {
        const short8 pf = *(const short8*)&Psw[lr][32*kc + 8*lg];
        #pragma unroll
        for (int mt = 0; mt < 4; ++mt) {
            const short8 vf = *(const short8*)&Vsb[16*mt + lr][32*kc + 8*lg];
            oacc[mt] = mfma16(vf, pf, oacc[mt]);
        }
    }
}

__global__ __launch_bounds__(256)
void attn_mfma(const short* __restrict__ Q, const short* __restrict__ K,
               const short* __restrict__ Vt, short* __restrict__ out)
{
    __shared__ __attribute__((aligned(16))) short Ks[2][64][PAD];  // [buf][k][d]
    __shared__ __attribute__((aligned(16))) short Vs[2][64][PAD];  // [buf][d][k]
    __shared__ __attribute__((aligned(16))) short Ps[4][16][PAD];  // per-wave [q][k]

    const int id = blockIdx.x;
    const int bh = id >> 4;            // head index (32)
    const int pr = id & 15;            // pair index
    const int qtA = pr, qtB = 31 - pr; // qtA in [0,15], qtB in [16,31]
    const int b = bh >> 4, h = bh & 15;
    const int tid = threadIdx.x;
    const int w = tid >> 6, l = tid & 63;
    const int lr = l & 15, lg = l >> 4;

    const short* Qp = Q  + (size_t)bh * T_ * D_;
    const short* Kp = K  + (size_t)bh * T_ * D_;
    const short* Vp = Vt + (size_t)bh * D_ * T_;

    // staging coords: thread owns rows {sr0, sr0+32}, 8-col chunk sc
    const int sr0 = tid >> 3;          // 0..31
    const int sc  = (tid & 7) * 8;     // 0..56

    // prologue: tile0 -> regs -> buf0; tile1 -> regs (qtB >= 16 so it exists)
    short8 kreg[2], vreg[2];
    kreg[0] = *(const short8*)(Kp + (size_t)sr0 * D_ + sc);
    kreg[1] = *(const short8*)(Kp + (size_t)(sr0 + 32) * D_ + sc);
    vreg[0] = *(const short8*)(Vp + (size_t)sr0 * T_ + sc);
    vreg[1] = *(const short8*)(Vp + (size_t)(sr0 + 32) * T_ + sc);
    *(short8*)&Ks[0][sr0][sc]      = kreg[0];
    *(short8*)&Ks[0][sr0 + 32][sc] = kreg[1];
    *(short8*)&Vs[0][sr0][sc]      = vreg[0];
    *(short8*)&Vs[0][sr0 + 32][sc] = vreg[1];
    kreg[0] = *(const short8*)(Kp + (size_t)(64 + sr0) * D_ + sc);
    kreg[1] = *(const short8*)(Kp + (size_t)(64 + sr0 + 32) * D_ + sc);
    vreg[0] = *(const short8*)(Vp + (size_t)sr0 * T_ + 64 + sc);
    vreg[1] = *(const short8*)(Vp + (size_t)(sr0 + 32) * T_ + 64 + sc);

    const int qrowA = qtA * 64 + 16*w + lr;
    const int qrowB = qtB * 64 + 16*w + lr;
    short8 qfragA[2], qfragB[2];
    {
        const short* qa = Qp + (size_t)qrowA * D_ + lg * 8;
        const short* qb = Qp + (size_t)qrowB * D_ + lg * 8;
        qfragA[0] = *(const short8*)(qa); qfragA[1] = *(const short8*)(qa + 32);
        qfragB[0] = *(const short8*)(qb); qfragB[1] = *(const short8*)(qb + 32);
    }

    float mA = -INFINITY, lA = 0.f, mB = -INFINITY, lB = 0.f;
    f32x4 oA[4] = {}, oB[4] = {};

    __syncthreads();   // buf0 visible to all waves

    for (int kt = 0; kt <= qtB; ++kt) {
        const int cb = kt & 1;
        // write tile kt+1 (in regs since last step) to the other buffer,
        // then issue loads for tile kt+2; both overlap this step's compute.
        if (kt < qtB) {
            *(short8*)&Ks[cb ^ 1][sr0][sc]      = kreg[0];
            *(short8*)&Ks[cb ^ 1][sr0 + 32][sc] = kreg[1];
            *(short8*)&Vs[cb ^ 1][sr0][sc]      = vreg[0];
            *(short8*)&Vs[cb ^ 1][sr0 + 32][sc] = vreg[1];
            if (kt + 1 < qtB) {
                const int k2 = (kt + 2) * 64;
                kreg[0] = *(const short8*)(Kp + (size_t)(k2 + sr0) * D_ + sc);
                kreg[1] = *(const short8*)(Kp + (size_t)(k2 + sr0 + 32) * D_ + sc);
                vreg[0] = *(const short8*)(Vp + (size_t)sr0 * T_ + k2 + sc);
                vreg[1] = *(const short8*)(Vp + (size_t)(sr0 + 32) * T_ + k2 + sc);
            }
        }

        const int k0 = kt * 64;
        if (kt <= qtA) {               // dual step: A and B share one region
            f32x4 sA[4] = {}, sB[4] = {};
            qk_phase(Ks[cb], qfragA, lr, lg, sA);
            qk_phase(Ks[cb], qfragB, lr, lg, sB);
            mfma_drain();              // one drain covers both
            if (kt == qtA)
                sm_pv_phase<true >(sA, Vs[cb], Ps[w], k0, qrowA, lr, lg, mA, lA, oA);
            else
                sm_pv_phase<false>(sA, Vs[cb], Ps[w], k0, qrowA, lr, lg, mA, lA, oA);
            sm_pv_phase<false>(sB, Vs[cb], Ps[w], k0, qrowB, lr, lg, mB, lB, oB);
        } else {                       // B-only step
            f32x4 sB[4] = {};
            qk_phase(Ks[cb], qfragB, lr, lg, sB);
            mfma_drain();
            if (kt == qtB)
                sm_pv_phase<true >(sB, Vs[cb], Ps[w], k0, qrowB, lr, lg, mB, lB, oB);
            else
                sm_pv_phase<false>(sB, Vs[cb], Ps[w], k0, qrowB, lr, lg, mB, lB, oB);
        }
        __syncthreads();               // next buffer fully written; LDS reuse safe
    }
    mfma_drain();

    const float invA = 1.f / lA;
    const float invB = 1.f / lB;
    short* opA = out + ((size_t)(b * T_ + qrowA)) * C_ + h * D_;
    short* opB = out + ((size_t)(b * T_ + qrowB)) * C_ + h * D_;
    #pragma unroll
    for (int mt = 0; mt < 4; ++mt) {
        short4v oa, ob;
        oa[0] = f2bf(oA[mt][0] * invA); oa[1] = f2bf(oA[mt][1] * invA);
        oa[2] = f2bf(oA[mt][2] * invA); oa[3] = f2bf(oA[mt][3] * invA);
        ob[0] = f2bf(oB[mt][0] * invB); ob[1] = f2bf(oB[mt][1] * invB);
        ob[2] = f2bf(oB[mt][2] * invB); ob[3] = f2bf(oB[mt][3] * invB);
        *(short4v*)&opA[16*mt + 4*lg] = oa;
        *(short4v*)&opB[16*mt + 4*lg] = ob;
    }
}

// ---------------------------------------------------------------------------
extern "C" void kernel_launch(void* const* d_in, const int* in_sizes, int n_in,
                              void* d_out, int out_size, void* d_ws, size_t ws_size,
                              hipStream_t stream) {
    const float* x  = (const float*)d_in[0];
    const float* Wq = (const float*)d_in[1];
    const float* bq = (const float*)d_in[2];
    const float* Wk = (const float*)d_in[3];
    const float* bk = (const float*)d_in[4];
    const float* Wv = (const float*)d_in[5];
    const float* bv = (const float*)d_in[6];
    const float* Wo = (const float*)d_in[7];
    const float* bo = (const float*)d_in[8];
    float* out = (float*)d_out;

    // bf16 workspace (els): x 4M | Wq..Wo 1M each | Q,K,V^T 4M each | ya 4M = 48MB
    short* xb  = (short*)d_ws;
    short* wqb = xb  + 4194304;
    short* wkb = wqb + 1048576;
    short* wvb = wkb + 1048576;
    short* wob = wvb + 1048576;
    short* qb  = wob + 1048576;
    short* kb  = qb  + 4194304;
    short* vb  = kb  + 4194304;   // V^T [B,H,D,T]
    short* yab = vb  + 4194304;   // [B,T,C]

    cvt_all<<<1024, 256, 0, stream>>>(x, Wq, Wk, Wv, Wo, xb, wqb, wkb, wvb, wob);
    qkv_gemm<<<dim3(32, 24), 256, 0, stream>>>(xb, wqb, wkb, wvb, bq, bk, bv,
                                               qb, kb, vb);
    attn_mfma<<<dim3(512), 256, 0, stream>>>(qb, kb, vb, yab);
    out_gemm<<<dim3(64, 8), 256, 0, stream>>>(yab, wob, bo, out);
}